// Round 5
// baseline (284.948 us; speedup 1.0000x reference)
//
#include <hip/hip_runtime.h>

typedef __bf16 bf16;
typedef __bf16 bf16x8 __attribute__((ext_vector_type(8)));
typedef __bf16 bf16x4 __attribute__((ext_vector_type(4)));
typedef float f32x4 __attribute__((ext_vector_type(4)));
typedef unsigned int uint;
typedef unsigned short ushort;

typedef const __attribute__((address_space(1))) void* gas_ptr;
typedef __attribute__((address_space(3))) void* las_ptr;

__device__ __forceinline__ void load16_lds(const void* g, void* l) {
  __builtin_amdgcn_global_load_lds((gas_ptr)g, (las_ptr)l, 16, 0, 0);
}

// ---------------------------------------------------------------------------
// x fp32 -> bf16 cast (8 elems/thread)
// ---------------------------------------------------------------------------
__global__ __launch_bounds__(256) void cast_f32_bf16(
    const float* __restrict__ in, bf16* __restrict__ out) {
  size_t i = (size_t)blockIdx.x * 256 + threadIdx.x;
  const float4* p = reinterpret_cast<const float4*>(in) + i * 2;
  float4 a = p[0], b = p[1];
  bf16x8 v;
  v[0] = (bf16)a.x; v[1] = (bf16)a.y; v[2] = (bf16)a.z; v[3] = (bf16)a.w;
  v[4] = (bf16)b.x; v[5] = (bf16)b.y; v[6] = (bf16)b.z; v[7] = (bf16)b.w;
  reinterpret_cast<bf16x8*>(out)[i] = v;
}

// ---------------------------------------------------------------------------
// Weight transpose + cast: in [K][N] fp32 -> out [N][K] bf16, 64x64 tiles
// ---------------------------------------------------------------------------
__global__ __launch_bounds__(256) void transpose_f32_bf16(
    const float* __restrict__ in, bf16* __restrict__ out, int K, int N) {
  __shared__ __attribute__((aligned(16))) bf16 tile[64 * 72];
  const int k0 = blockIdx.y * 64, n0 = blockIdx.x * 64;
  const int tid = threadIdx.x;
  for (int c = tid; c < 1024; c += 256) {
    int ki = c >> 4, j4 = c & 15;
    float4 f = *reinterpret_cast<const float4*>(in + (size_t)(k0 + ki) * N + n0 + j4 * 4);
    bf16* t = &tile[ki * 72 + j4 * 4];
    t[0] = (bf16)f.x; t[1] = (bf16)f.y; t[2] = (bf16)f.z; t[3] = (bf16)f.w;
  }
  __syncthreads();
  for (int c = tid; c < 512; c += 256) {
    int ni = c >> 3, k8 = c & 7;
    bf16x8 v;
    for (int j = 0; j < 8; j++) v[j] = tile[(k8 * 8 + j) * 72 + ni];
    *reinterpret_cast<bf16x8*>(out + (size_t)(n0 + ni) * K + k0 + k8 * 8) = v;
  }
}

// ---------------------------------------------------------------------------
// GEMM: C[M,N] = A[M,K] * Bt[N,K]^T  (bf16 in, f32 accum, CT out)
// 128x128 tile, BK=64. Staging via global_load_lds width=16.
// XCD-aware bijective block swizzle (T1): nwg % 8 == 0 guaranteed by launcher.
// ---------------------------------------------------------------------------
template <typename CT>
__global__ __launch_bounds__(256, 2) void gemm_lds(
    const bf16* __restrict__ A, const bf16* __restrict__ Bt,
    CT* __restrict__ C, int M, int N, int K) {
  __shared__ __attribute__((aligned(16))) bf16 As[128 * 64];
  __shared__ __attribute__((aligned(16))) bf16 Bs[128 * 64];
  const int tid = threadIdx.x;
  const int wave = tid >> 6;
  const int lane = tid & 63;
  const int l15 = lane & 15;
  const int quad = lane >> 4;
  const int nwg = gridDim.x * gridDim.y;
  const int orig = blockIdx.y * gridDim.x + blockIdx.x;
  const int swz = (orig & 7) * (nwg >> 3) + (orig >> 3);
  const int m0 = (swz / gridDim.x) * 128;
  const int n0 = (swz % gridDim.x) * 128;
  const int wm = (wave >> 1) * 64;
  const int wn = (wave & 1) * 64;

  f32x4 acc[4][4] = {};

  for (int kt = 0; kt < K; kt += 64) {
    __syncthreads();
    for (int it = 0; it < 4; ++it) {
      int p = it * 256 + wave * 64 + lane;
      int row = p >> 3, kc = (p & 7) ^ (row & 7);
      load16_lds(A + (size_t)(m0 + row) * K + kt + kc * 8, &As[p * 8]);
      load16_lds(Bt + (size_t)(n0 + row) * K + kt + kc * 8, &Bs[p * 8]);
    }
    __syncthreads();
    for (int kk = 0; kk < 64; kk += 32) {
      const int kc = (kk >> 3) + quad;
      bf16x8 af[4], bfr[4];
      for (int i = 0; i < 4; i++) {
        int row = wm + i * 16 + l15;
        af[i] = *reinterpret_cast<const bf16x8*>(&As[(row * 8 + (kc ^ (row & 7))) * 8]);
      }
      for (int j = 0; j < 4; j++) {
        int row = wn + j * 16 + l15;
        bfr[j] = *reinterpret_cast<const bf16x8*>(&Bs[(row * 8 + (kc ^ (row & 7))) * 8]);
      }
      for (int i = 0; i < 4; i++)
        for (int j = 0; j < 4; j++)
          acc[i][j] = __builtin_amdgcn_mfma_f32_16x16x32_bf16(af[i], bfr[j], acc[i][j], 0, 0, 0);
    }
  }

  for (int i = 0; i < 4; i++)
    for (int j = 0; j < 4; j++)
      for (int r = 0; r < 4; r++) {
        int row = m0 + wm + i * 16 + quad * 4 + r;
        int col = n0 + wn + j * 16 + l15;
        C[(size_t)row * N + col] = (CT)acc[i][j][r];
      }
}

// ---------------------------------------------------------------------------
// Flash attention, swapped-QK^T, 2 q-streams/wave. qkv: [B*T, 3072] bf16.
// Grid (B*H=64, T/256=8); 8 waves x 32 q-rows (stream A: qt0+w*16, B: +128).
// K staged by global_load_lds (per-lane source pre-composed with inverse-rho
// + XOR-chunk; LDS bytes identical to the HW-verified round-2 layout).
// V staged by all 8 waves (4 dword-packs/thread) into swizzled Vs.
// Double-buffered, ONE barrier per tile. In-register softmax + defer-max.
// Stream order QK_A,QK_B,smA,PV_A,smB,PV_B gives in-wave MFMA/VALU overlap.
// ---------------------------------------------------------------------------
__device__ __forceinline__ int vs_dw(int d, int kdw) {
  return d * 32 + (kdw ^ ((((d >> 3) ^ d) & 7) * 4));
}

__global__ __launch_bounds__(512, 2) void attn_kernel(
    const bf16* __restrict__ qkv, bf16* __restrict__ out) {
  __shared__ __attribute__((aligned(16))) bf16 Ks[2][64 * 64];  // XOR-chunk, rho-rows
  __shared__ __attribute__((aligned(16))) uint Vs[2][64 * 32];  // swizzled [d][keypair]

  const int tid = threadIdx.x;
  const int wave = tid >> 6;    // 0..7
  const int lane = tid & 63;
  const int l15 = lane & 15;
  const int quad = lane >> 4;
  const int b = blockIdx.x >> 4;
  const int h = blockIdx.x & 15;
  const int qt0 = blockIdx.y * 256;
  const bf16* base = qkv + (size_t)b * 2048 * 3072 + h * 64;
  const float L2E = 1.44269504f;

  // Q fragments for both streams, pre-scaled by log2(e)
  bf16x8 aqA0, aqA1, aqB0, aqB1;
  {
    const bf16* qa = base + (size_t)(qt0 + wave * 16 + l15) * 3072;
    const bf16* qb = qa + (size_t)128 * 3072;
    aqA0 = *reinterpret_cast<const bf16x8*>(qa + quad * 8);
    aqA1 = *reinterpret_cast<const bf16x8*>(qa + 32 + quad * 8);
    aqB0 = *reinterpret_cast<const bf16x8*>(qb + quad * 8);
    aqB1 = *reinterpret_cast<const bf16x8*>(qb + 32 + quad * 8);
    for (int j = 0; j < 8; j++) {
      aqA0[j] = (bf16)((float)aqA0[j] * L2E);
      aqA1[j] = (bf16)((float)aqA1[j] * L2E);
      aqB0[j] = (bf16)((float)aqB0[j] * L2E);
      aqB1[j] = (bf16)((float)aqB1[j] * L2E);
    }
  }

  // ones-column B fragment: B[k][0] = 1 -> lanes with l15==0 hold 1s
  bf16x8 bones = {};
  if (l15 == 0)
    for (int j = 0; j < 8; j++) bones[j] = (bf16)1.0f;

  float mA = -1e30f, mB = -1e30f;
  f32x4 oA[4] = {}, oB[4] = {};
  f32x4 lA = {}, lB = {};

  // ---- K staging: global_load_lds, 1 chunk (16B) per thread ----
  // LDS chunk c holds (lds_row = c>>3, kc = (c&7)^(row&7)); lds_row r holds
  // true key inv_rho(r): bit2<-r4, bit4<-r3, bit3<-r2, bits1:0<-r1:0, bit5<-r5.
  const int c = tid;                 // 0..511
  const int krow = c >> 3;
  const int kc8 = (c & 7) ^ (krow & 7);
  const int ktrue = (((krow >> 4) & 1) << 2) | (((krow >> 3) & 1) << 4) |
                    (((krow >> 2) & 1) << 3) | (krow & 3) | (krow & 32);
  const bf16* kgp = base + 1024 + (size_t)ktrue * 3072 + kc8 * 8;

  // ---- V staging: 4 dword-packs per thread ----
  const int vkp = tid >> 4;          // keypair 0..31
  const int vd0 = (tid & 15) * 4;    // d base 0..60
  const bf16* vgp = base + (size_t)(2 * vkp) * 3072 + 2048 + vd0;

  // ---- prologue: tile 0 ----
  load16_lds(kgp, &Ks[0][c * 8]);
  bf16x4 vpre0 = *reinterpret_cast<const bf16x4*>(vgp);
  bf16x4 vpre1 = *reinterpret_cast<const bf16x4*>(vgp + 3072);

  for (int kt = 0; kt < 2048; kt += 64) {
    const int cur = (kt >> 6) & 1;
    // write prefetched V (tile t) into Vs[cur]
    {
      const ushort* u0 = reinterpret_cast<const ushort*>(&vpre0);
      const ushort* u1 = reinterpret_cast<const ushort*>(&vpre1);
      for (int i = 0; i < 4; i++)
        Vs[cur][vs_dw(vd0 + i, vkp)] = (uint)u0[i] | ((uint)u1[i] << 16);
    }
    __syncthreads();   // V visible; K DMA (issued last iter) drained

    // issue next-tile staging; latency hides under compute
    if (kt + 64 < 2048) {
      const size_t off = (size_t)(kt + 64) * 3072;
      load16_lds(kgp + off, &Ks[cur ^ 1][c * 8]);
      vpre0 = *reinterpret_cast<const bf16x4*>(vgp + off);
      vpre1 = *reinterpret_cast<const bf16x4*>(vgp + off + 3072);
    }

    // ---- QK^T (swapped) for both streams ----
    f32x4 sA[4], sB[4];
    __builtin_amdgcn_s_setprio(1);
    for (int n = 0; n < 4; n++) {
      int row = n * 16 + l15;
      int xr = row & 7;
      bf16x8 ak0 = *reinterpret_cast<const bf16x8*>(&Ks[cur][(row * 8 + (quad ^ xr)) * 8]);
      bf16x8 ak1 = *reinterpret_cast<const bf16x8*>(&Ks[cur][(row * 8 + ((4 + quad) ^ xr)) * 8]);
      f32x4 z = {};
      z = __builtin_amdgcn_mfma_f32_16x16x32_bf16(ak0, aqA0, z, 0, 0, 0);
      z = __builtin_amdgcn_mfma_f32_16x16x32_bf16(ak1, aqA1, z, 0, 0, 0);
      sA[n] = z;
      f32x4 w = {};
      w = __builtin_amdgcn_mfma_f32_16x16x32_bf16(ak0, aqB0, w, 0, 0, 0);
      w = __builtin_amdgcn_mfma_f32_16x16x32_bf16(ak1, aqB1, w, 0, 0, 0);
      sB[n] = w;
    }
    __builtin_amdgcn_s_setprio(0);

    // ---- stream A: softmax + rowsum + PV ----
    {
      float mt = fmaxf(fmaxf(sA[0][0], sA[0][1]), sA[0][2]);
      mt = fmaxf(fmaxf(mt, sA[0][3]), sA[1][0]);
      mt = fmaxf(fmaxf(mt, sA[1][1]), sA[1][2]);
      mt = fmaxf(fmaxf(mt, sA[1][3]), sA[2][0]);
      mt = fmaxf(fmaxf(mt, sA[2][1]), sA[2][2]);
      mt = fmaxf(fmaxf(mt, sA[2][3]), sA[3][0]);
      mt = fmaxf(fmaxf(mt, sA[3][1]), sA[3][2]);
      mt = fmaxf(mt, sA[3][3]);
      mt = fmaxf(mt, __shfl_xor(mt, 16, 64));
      mt = fmaxf(mt, __shfl_xor(mt, 32, 64));
      if (!__all(mt - mA <= 8.0f)) {
        float mn = fmaxf(mA, mt);
        float alpha = __builtin_amdgcn_exp2f(mA - mn);
        mA = mn;
        float a0 = __shfl(alpha, quad * 4 + 0, 64);
        float a1 = __shfl(alpha, quad * 4 + 1, 64);
        float a2 = __shfl(alpha, quad * 4 + 2, 64);
        float a3 = __shfl(alpha, quad * 4 + 3, 64);
        lA[0] *= a0; lA[1] *= a1; lA[2] *= a2; lA[3] *= a3;
        for (int n = 0; n < 4; n++) {
          oA[n][0] *= a0; oA[n][1] *= a1; oA[n][2] *= a2; oA[n][3] *= a3;
        }
      }
      bf16x8 ap0, ap1;
      for (int r = 0; r < 4; r++) {
        ap0[r]     = (bf16)__builtin_amdgcn_exp2f(sA[0][r] - mA);
        ap0[4 + r] = (bf16)__builtin_amdgcn_exp2f(sA[1][r] - mA);
        ap1[r]     = (bf16)__builtin_amdgcn_exp2f(sA[2][r] - mA);
        ap1[4 + r] = (bf16)__builtin_amdgcn_exp2f(sA[3][r] - mA);
      }
      __builtin_amdgcn_s_setprio(1);
      lA = __builtin_amdgcn_mfma_f32_16x16x32_bf16(ap0, bones, lA, 0, 0, 0);
      lA = __builtin_amdgcn_mfma_f32_16x16x32_bf16(ap1, bones, lA, 0, 0, 0);
      for (int n = 0; n < 4; n++) {
        int d = n * 16 + l15;
        uint4 u0 = *reinterpret_cast<const uint4*>(&Vs[cur][vs_dw(d, quad * 4)]);
        uint4 u1 = *reinterpret_cast<const uint4*>(&Vs[cur][vs_dw(d, 16 + quad * 4)]);
        bf16x8 bv0 = *reinterpret_cast<const bf16x8*>(&u0);
        bf16x8 bv1 = *reinterpret_cast<const bf16x8*>(&u1);
        oA[n] = __builtin_amdgcn_mfma_f32_16x16x32_bf16(ap0, bv0, oA[n], 0, 0, 0);
        oA[n] = __builtin_amdgcn_mfma_f32_16x16x32_bf16(ap1, bv1, oA[n], 0, 0, 0);
      }
      __builtin_amdgcn_s_setprio(0);
    }

    // ---- stream B: softmax + rowsum + PV (overlaps A's MFMA tail) ----
    {
      float mt = fmaxf(fmaxf(sB[0][0], sB[0][1]), sB[0][2]);
      mt = fmaxf(fmaxf(mt, sB[0][3]), sB[1][0]);
      mt = fmaxf(fmaxf(mt, sB[1][1]), sB[1][2]);
      mt = fmaxf(fmaxf(mt, sB[1][3]), sB[2][0]);
      mt = fmaxf(fmaxf(mt, sB[2][1]), sB[2][2]);
      mt = fmaxf(fmaxf(mt, sB[2][3]), sB[3][0]);
      mt = fmaxf(fmaxf(mt, sB[3][1]), sB[3][2]);
      mt = fmaxf(mt, sB[3][3]);
      mt = fmaxf(mt, __shfl_xor(mt, 16, 64));
      mt = fmaxf(mt, __shfl_xor(mt, 32, 64));
      if (!__all(mt - mB <= 8.0f)) {
        float mn = fmaxf(mB, mt);
        float alpha = __builtin_amdgcn_exp2f(mB - mn);
        mB = mn;
        float a0 = __shfl(alpha, quad * 4 + 0, 64);
        float a1 = __shfl(alpha, quad * 4 + 1, 64);
        float a2 = __shfl(alpha, quad * 4 + 2, 64);
        float a3 = __shfl(alpha, quad * 4 + 3, 64);
        lB[0] *= a0; lB[1] *= a1; lB[2] *= a2; lB[3] *= a3;
        for (int n = 0; n < 4; n++) {
          oB[n][0] *= a0; oB[n][1] *= a1; oB[n][2] *= a2; oB[n][3] *= a3;
        }
      }
      bf16x8 ap0, ap1;
      for (int r = 0; r < 4; r++) {
        ap0[r]     = (bf16)__builtin_amdgcn_exp2f(sB[0][r] - mB);
        ap0[4 + r] = (bf16)__builtin_amdgcn_exp2f(sB[1][r] - mB);
        ap1[r]     = (bf16)__builtin_amdgcn_exp2f(sB[2][r] - mB);
        ap1[4 + r] = (bf16)__builtin_amdgcn_exp2f(sB[3][r] - mB);
      }
      __builtin_amdgcn_s_setprio(1);
      lB = __builtin_amdgcn_mfma_f32_16x16x32_bf16(ap0, bones, lB, 0, 0, 0);
      lB = __builtin_amdgcn_mfma_f32_16x16x32_bf16(ap1, bones, lB, 0, 0, 0);
      for (int n = 0; n < 4; n++) {
        int d = n * 16 + l15;
        uint4 u0 = *reinterpret_cast<const uint4*>(&Vs[cur][vs_dw(d, quad * 4)]);
        uint4 u1 = *reinterpret_cast<const uint4*>(&Vs[cur][vs_dw(d, 16 + quad * 4)]);
        bf16x8 bv0 = *reinterpret_cast<const bf16x8*>(&u0);
        bf16x8 bv1 = *reinterpret_cast<const bf16x8*>(&u1);
        oB[n] = __builtin_amdgcn_mfma_f32_16x16x32_bf16(ap0, bv0, oB[n], 0, 0, 0);
        oB[n] = __builtin_amdgcn_mfma_f32_16x16x32_bf16(ap1, bv1, oB[n], 0, 0, 0);
      }
      __builtin_amdgcn_s_setprio(0);
    }
  }

  for (int r = 0; r < 4; r++) {
    float lvA = __shfl(lA[r], quad * 16, 64);
    float invA = 1.0f / lvA;
    int qA = qt0 + wave * 16 + quad * 4 + r;
    bf16* orowA = out + (size_t)(b * 2048 + qA) * 1024 + h * 64;
    for (int n = 0; n < 4; n++) orowA[n * 16 + l15] = (bf16)(oA[n][r] * invA);

    float lvB = __shfl(lB[r], quad * 16, 64);
    float invB = 1.0f / lvB;
    bf16* orowB = orowA + (size_t)128 * 1024;
    for (int n = 0; n < 4; n++) orowB[n * 16 + l15] = (bf16)(oB[n][r] * invB);
  }
}

// ---------------------------------------------------------------------------
// Launch
// ---------------------------------------------------------------------------
extern "C" void kernel_launch(void* const* d_in, const int* in_sizes, int n_in,
                              void* d_out, int out_size, void* d_ws, size_t ws_size,
                              hipStream_t stream) {
  const float* x = (const float*)d_in[0];       // [8192, 1024] fp32
  const float* w_qkv = (const float*)d_in[1];   // [1024, 3072] fp32
  const float* w_proj = (const float*)d_in[2];  // [1024, 1024] fp32
  float* out = (float*)d_out;                   // [8192, 1024] fp32

  bf16* ws = (bf16*)d_ws;
  bf16* x_bf = ws;                                   // [8192,1024]
  bf16* wqkvT = x_bf + (size_t)8192 * 1024;          // [3072,1024]
  bf16* wprojT = wqkvT + 3072 * 1024;                // [1024,1024]
  bf16* qkv = wprojT + 1024 * 1024;                  // [8192,3072]
  bf16* attn_out = qkv + (size_t)8192 * 3072;        // [8192,1024]

  cast_f32_bf16<<<4096, 256, 0, stream>>>(x, x_bf);
  transpose_f32_bf16<<<dim3(48, 16), 256, 0, stream>>>(w_qkv, wqkvT, 1024, 3072);
  transpose_f32_bf16<<<dim3(16, 16), 256, 0, stream>>>(w_proj, wprojT, 1024, 1024);
  gemm_lds<bf16><<<dim3(24, 64), 256, 0, stream>>>(x_bf, wqkvT, qkv, 8192, 3072, 1024);
  attn_kernel<<<dim3(64, 8), 512, 0, stream>>>(qkv, attn_out);
  gemm_lds<float><<<dim3(8, 64), 256, 0, stream>>>(attn_out, wprojT, out, 8192, 1024, 1024);
}